// Round 9
// baseline (744.345 us; speedup 1.0000x reference)
//
#include <hip/hip_runtime.h>

// DecoderLSTM: B=4096, T=128 (127 steps), H=128, 4H=512, V=30, E=256.
// R9: 4 waves/SIMD from ONE block (R6-R8 showed 2 blocks/CU + 64-AGPR frags
// always spills). 256 blocks x 1024 thr (16 waves) x 16 rows. Each wave holds
// only 8 W_hh frags (32 regs): waves 0-7 gates (i,f) for cols w*16, waves
// 8-15 gates (g,o) same cols. 4-gate join = lane-aligned LDS exchange
// (float4 write+read, same lane id both sides) + 2nd barrier. Pointwise =
// 2 cells/lane on ALL waves (trans floor spread over 4 waves/SIMD). Logits
// kt-split on waves 0-7 (+1 MFMA, partials->LDS dbuf); softmax waves 14-15
// (R8 scheme); mask-sum wave 13. Full M=16 MFMA. Regs ~110 < 128 cap.

typedef __bf16 bf16x8 __attribute__((ext_vector_type(8)));
typedef float  f32x4  __attribute__((ext_vector_type(4)));

namespace {
constexpr int Bn = 4096, Tn = 128, Vn = 30, En = 256, Hn = 128, Gn = 512;
constexpr int WS_LOSS  = 0;
constexpr int WS_MASK  = 1;
constexpr int WS_CNT   = 2;
constexpr int WS_XPROJ = 16;                  // 30*512 fp32, layout [v][k][g]
constexpr int WS_WF_F  = WS_XPROJ + Vn * Gn;  // 65536 bf16 Whh-frags + 4096 bf16 Wlin-frags
constexpr int NBLK = 256;                     // 16 rows per block
}

__device__ __forceinline__ float fexp2(float x) { return __builtin_amdgcn_exp2f(x); }
__device__ __forceinline__ float frcp(float x)  { return __builtin_amdgcn_rcpf(x); }
__device__ __forceinline__ float sigf(float x)  { return frcp(1.f + fexp2(x * -1.44269504f)); }
__device__ __forceinline__ float tanh_(float x) { return 1.f - 2.f * frcp(fexp2(x * 2.88539008f) + 1.f); }

// ---- setup, 94 blocks x 256 (unchanged; zeroes loss/mask/cnt)
__global__ void k_setup(const float* __restrict__ emb, const float* __restrict__ W_ih,
                        const float* __restrict__ b_ih, const float* __restrict__ b_hh,
                        const float* __restrict__ W_hh, const float* __restrict__ W_lin,
                        float* __restrict__ ws) {
  const int bid = blockIdx.x, tid = threadIdx.x;
  if (bid < 60) {
    __shared__ __align__(16) float es[En];
    int v = bid >> 1;
    int j = ((bid & 1) << 8) + tid;   // j = g*128 + k
    es[tid] = emb[v * En + tid];
    __syncthreads();
    float a = b_ih[j] + b_hh[j];
    const float* wr = W_ih + j * En;
#pragma unroll 4
    for (int e = 0; e < En; e += 4) {
      float4 w = *(const float4*)(wr + e);
      float4 x = *(const float4*)(es + e);
      a += x.x * w.x + x.y * w.y + x.z * w.z + x.w * w.w;
    }
    ws[WS_XPROJ + v * Gn + (j & 127) * 4 + (j >> 7)] = a;
  } else if (bid < 92) {
    int fid = (bid - 60) * 256 + tid;  // 0..8191
    int l = fid & 63, kt = (fid >> 6) & 3, g = (fid >> 8) & 3, w = fid >> 10;
    int n  = (g * 8 + w) * 16 + (l & 15);
    int k0 = kt * 32 + (l >> 4) * 8;
    const float* src = W_hh + n * Hn + k0;
    union { __bf16 h[8]; uint4 u; } pk;
#pragma unroll
    for (int j = 0; j < 8; ++j) pk.h[j] = (__bf16)src[j];
    __bf16* wf = (__bf16*)(ws + WS_WF_F);
    *(uint4*)(wf + fid * 8) = pk.u;
  } else {
    int fid = (bid - 92) * 256 + tid;  // 0..511
    if (fid < 3) ws[fid] = 0.f;        // WS_LOSS, WS_MASK, WS_CNT
    int l = fid & 63, kt = (fid >> 6) & 3, n = fid >> 8;
    int col = n * 16 + (l & 15);
    int k0  = kt * 32 + (l >> 4) * 8;
    union { __bf16 h[8]; uint4 u; } pk;
#pragma unroll
    for (int j = 0; j < 8; ++j)
      pk.h[j] = (col < Vn) ? (__bf16)W_lin[col * Hn + k0 + j] : (__bf16)0.f;
    __bf16* wf = (__bf16*)(ws + WS_WF_F);
    *(uint4*)(wf + 65536 + fid * 8) = pk.u;
  }
}

// ---- main: 256 blocks x 1024 threads (16 waves), 16 batch rows/block
__global__ __launch_bounds__(1024, 4) void k_main(
    const int* __restrict__ inpt, const float* __restrict__ h0,
    const float* __restrict__ c0, const float* __restrict__ maskY,
    const float* __restrict__ b_lin, float* __restrict__ ws,
    float* __restrict__ out) {
  __shared__ __align__(16) __bf16 hbuf[2][16][136];
  __shared__ int   tokL[16 * 129];
  __shared__ float maskL[16 * 132];
  __shared__ __align__(16) float lgP[2][8][256];   // [dbuf][kt*2+nt][lane*4+reg]
  __shared__ __align__(16) float gx[8][64][4];     // GO->IF: {g0,g1,o0,o1} (p=0,1)
  __shared__ __align__(16) float ix[8][64][4];     // IF->GO: {i2,i3,f2,f3} (p=2,3)
  __shared__ float blinL[32];
  __shared__ float red[4];

  const float4* X4  = (const float4*)(ws + WS_XPROJ); // [v*128+k] -> (i,f,g,o)
  const __bf16* wf  = (const __bf16*)(ws + WS_WF_F);
  const __bf16* wlf = wf + 65536;

  const int tid = threadIdx.x;
  const int w = tid >> 6, l = tid & 63, quad = l >> 4, lc = l & 15;
  const int row0 = blockIdx.x * 16;
  const bool isIF = (w < 8);
  const int cw = w & 7;            // col-range index
  const int kh = cw * 16 + lc;     // owned column (within each gate)
  const int prB = isIF ? 0 : 2;    // pointwise p-base: IF rows +0/+1, GO +2/+3
  const int lnt = (w >> 2) & 1, lkt = w & 3;   // logits assignment (IF only)

  // staging
  for (int idx = tid; idx < 16 * Tn; idx += 1024) {
    int r = idx >> 7, t = idx & 127;
    tokL[r * 129 + t]  = inpt[(row0 + r) * Tn + t];
    maskL[r * 132 + t] = maskY[(row0 + r) * Tn + t];
  }
  for (int idx = tid; idx < 16 * Hn; idx += 1024) {
    int r = idx >> 7, k = idx & 127;
    hbuf[0][r][k] = (__bf16)h0[(row0 + r) * Hn + k];
  }
  if (tid < 32) blinL[tid] = (tid < Vn) ? b_lin[tid] : -1e30f;

  // persistent frags: 2 gate-ntiles (8 frags = 32 regs) + 1 W_lin frag
  // ntile n -> setup frag id: g=n>>3, wv=n&7, fid=((wv*4+g)*4+kt)*64+l
  const int n0 = isIF ? cw : 16 + cw;       // i or g
  const int n1 = isIF ? 8 + cw : 24 + cw;   // f or o
  bf16x8 wreg[2][4];
#pragma unroll
  for (int kt = 0; kt < 4; ++kt) {
    wreg[0][kt] = __builtin_bit_cast(bf16x8,
        *(const uint4*)(wf + ((((n0 & 7) * 4 + (n0 >> 3)) * 4 + kt) * 64 + l) * 8));
    wreg[1][kt] = __builtin_bit_cast(bf16x8,
        *(const uint4*)(wf + ((((n1 & 7) * 4 + (n1 >> 3)) * 4 + kt) * 64 + l) * 8));
  }
  bf16x8 wlin = __builtin_bit_cast(bf16x8,
      *(const uint4*)(wlf + ((isIF ? (lnt * 4 + lkt) : 0) * 64 + l) * 8));

  float creg[2];
#pragma unroll
  for (int p = 0; p < 2; ++p)
    creg[p] = c0[(row0 + quad * 4 + prB + p) * Hn + kh];

  float mloc = 0.f;
  if (w == 13) {  // block mask sum: 16 rows x 128 = 512 float4
    float s = 0.f;
    const float4* m4 = (const float4*)(maskY + row0 * Tn);
#pragma unroll
    for (int i = 0; i < 8; ++i) s += m4[l + i * 64].x + m4[l + i * 64].y +
                                     m4[l + i * 64].z + m4[l + i * 64].w;
    mloc = s;
  }
  float ce_acc = 0.f;
  __syncthreads();

  for (int t = 0; t <= Tn; ++t) {  // gates t<=126, logits 1<=t<=127, softmax t>=2
    const int par = t & 1;
    const __bf16* hc = &hbuf[par][0][0];
    __bf16*       hn = &hbuf[par ^ 1][0][0];
    const bool do_g = (t <= Tn - 2);
    const bool do_l = isIF && (t >= 1) && (t <= Tn - 1);

    float4 xv[4];
    if (do_g) {  // Xproj issued first (L2 latency hidden behind MFMA)
#pragma unroll
      for (int p = 0; p < 4; ++p)
        xv[p] = X4[tokL[(quad * 4 + p) * 129 + t] * 128 + kh];
    }
    f32x4 acc[2] = {{0, 0, 0, 0}, {0, 0, 0, 0}};
    if (do_g || do_l) {
      bf16x8 af[4];
#pragma unroll
      for (int kt = 0; kt < 4; ++kt)
        af[kt] = __builtin_bit_cast(bf16x8,
            *(const uint4*)(hc + lc * 136 + kt * 32 + quad * 8));
      if (do_g) {
#pragma unroll
        for (int kt = 0; kt < 4; ++kt) {
          acc[0] = __builtin_amdgcn_mfma_f32_16x16x32_bf16(af[kt], wreg[0][kt], acc[0], 0, 0, 0);
          acc[1] = __builtin_amdgcn_mfma_f32_16x16x32_bf16(af[kt], wreg[1][kt], acc[1], 0, 0, 0);
        }
      }
      if (do_l) {
        f32x4 lacc = {0, 0, 0, 0};
        lacc = __builtin_amdgcn_mfma_f32_16x16x32_bf16(af[lkt], wlin, lacc, 0, 0, 0);
        *(f32x4*)&lgP[par][lkt * 2 + lnt][l * 4] = lacc;
      }
    }
    if (do_g) {
      // add Xproj for this wave's 2 gates, all 4 p
#pragma unroll
      for (int p = 0; p < 4; ++p) {
        acc[0][p] += isIF ? xv[p].x : xv[p].z;
        acc[1][p] += isIF ? xv[p].y : xv[p].w;
      }
      // exchange halves (lane-aligned: same lane id = same (row,col) cell)
      if (isIF)
        *(float4*)&ix[cw][l][0] = float4{acc[0][2], acc[0][3], acc[1][2], acc[1][3]};
      else
        *(float4*)&gx[cw][l][0] = float4{acc[0][0], acc[0][1], acc[1][0], acc[1][1]};
    }
    __syncthreads();  // barrier 1: gate halves exchanged

    if (do_g) {
      float4 pr = isIF ? *(const float4*)&gx[cw][l][0]
                       : *(const float4*)&ix[cw][l][0];
#pragma unroll
      for (int p = 0; p < 2; ++p) {
        float gi = isIF ? acc[0][p] : ((const float*)&pr)[p];
        float gf = isIF ? acc[1][p] : ((const float*)&pr)[2 + p];
        float gg = isIF ? ((const float*)&pr)[p]     : acc[0][p];
        float go = isIF ? ((const float*)&pr)[2 + p] : acc[1][p];
        float c2 = sigf(gf) * creg[p] + sigf(gi) * tanh_(gg);
        float h2 = sigf(go) * tanh_(c2);
        creg[p] = c2;
        hn[(quad * 4 + prB + p) * 136 + kh] = (__bf16)h2;
      }
    }

    // softmax+CE of previous step's logits (waves 14,15; 8 rows each)
    if (w >= 14 && t >= 2) {
      const float* P = &lgP[par ^ 1][0][0];
      int r8 = l >> 3, j = l & 7;
      int row = (w - 14) * 8 + r8;
      float lg[4], mx = -3.4e38f;
#pragma unroll
      for (int i = 0; i < 4; ++i) {
        int v = j * 4 + i;
        int li = ((row >> 2) * 16 + (v & 15)) * 4 + (row & 3);
        float s = blinL[v];
#pragma unroll
        for (int kt = 0; kt < 4; ++kt) s += P[(kt * 2 + (v >> 4)) * 256 + li];
        lg[i] = s;
        mx = fmaxf(mx, s);
      }
      mx = fmaxf(mx, __shfl_xor(mx, 1));
      mx = fmaxf(mx, __shfl_xor(mx, 2));
      mx = fmaxf(mx, __shfl_xor(mx, 4));
      int y = tokL[row * 129 + (t - 1)];
      float e = 0.f, ly = 0.f;
#pragma unroll
      for (int i = 0; i < 4; ++i) {
        e  += fexp2((lg[i] - mx) * 1.44269504f);
        ly += (j * 4 + i == y) ? lg[i] : 0.f;
      }
      e  += __shfl_xor(e, 1);  ly += __shfl_xor(ly, 1);
      e  += __shfl_xor(e, 2);  ly += __shfl_xor(ly, 2);
      e  += __shfl_xor(e, 4);  ly += __shfl_xor(ly, 4);
      if (j == 0)
        ce_acc += ((mx + __logf(e)) - ly) * maskL[row * 132 + (t - 2)];
    }
    __syncthreads();  // barrier 2: h(t+1) published / lgP dbuf safe
  }

  // final reductions
  if (w == 13) {
#pragma unroll
    for (int off = 32; off > 0; off >>= 1) mloc += __shfl_down(mloc, off);
    if (l == 0) red[0] = mloc;
  }
  if (w >= 14) {
#pragma unroll
    for (int off = 32; off > 0; off >>= 1) ce_acc += __shfl_down(ce_acc, off);
    if (l == 0) red[1 + (w - 14)] = ce_acc;
  }
  __syncthreads();
  if (tid == 0) {
    atomicAdd(ws + WS_LOSS, red[1] + red[2]);
    atomicAdd(ws + WS_MASK, red[0]);
    __threadfence();
    unsigned old = atomicAdd((unsigned*)(ws + WS_CNT), 1u);
    if (old == NBLK - 1) {  // last block publishes
      float lv  = atomicAdd(ws + WS_LOSS, 0.f);
      float mv2 = atomicAdd(ws + WS_MASK, 0.f);
      out[0] = lv / mv2;
    }
  }
}

extern "C" void kernel_launch(void* const* d_in, const int* in_sizes, int n_in,
                              void* d_out, int out_size, void* d_ws, size_t ws_size,
                              hipStream_t stream) {
  const int*   inpt  = (const int*)  d_in[0];
  const float* h0    = (const float*)d_in[1];
  const float* c0    = (const float*)d_in[2];
  const float* maskY = (const float*)d_in[3];
  // d_in[4] = beta (unused)
  const float* emb   = (const float*)d_in[5];
  const float* W_ih  = (const float*)d_in[6];
  const float* b_ih  = (const float*)d_in[7];
  const float* W_hh  = (const float*)d_in[8];
  const float* b_hh  = (const float*)d_in[9];
  const float* W_lin = (const float*)d_in[10];
  const float* b_lin = (const float*)d_in[11];
  float* ws  = (float*)d_ws;
  float* out = (float*)d_out;

  hipLaunchKernelGGL(k_setup, dim3(94),   dim3(256),  0, stream,
                     emb, W_ih, b_ih, b_hh, W_hh, W_lin, ws);
  hipLaunchKernelGGL(k_main,  dim3(NBLK), dim3(1024), 0, stream,
                     inpt, h0, c0, maskY, b_lin, ws, out);
}

// Round 10
// 570.550 us; speedup vs baseline: 1.3046x; 1.3046x over previous
//
#include <hip/hip_runtime.h>

// DecoderLSTM: B=4096, T=128 (127 steps), H=128, 4H=512, V=30, E=256.
// R10 = R9 (verified-correct 16-wave single-block layout) + the register-
// allocator fix: amdgpu_waves_per_eu(4,4) pins EXACTLY 4 waves/EU so the
// compiler grants the full 128-reg tier (R8/R9 evidence: with only a
// launch_bounds min, the allocator overshoots to the 64-reg/8-wave tier and
// spills). W_hh lives in the CU register file exactly once: 16 waves x 8
// frags (32 AGPR each). Xproj loads are float2 (each wave needs only its 2
// gate components). 256 blocks x 1024 thr x 16 rows; waves 0-7 gates (i,f),
// waves 8-15 gates (g,o); 4-gate join via lane-aligned LDS exchange; logits
// kt-split on waves 0-7; softmax on waves 14-15; 2 barriers/step.

typedef __bf16 bf16x8 __attribute__((ext_vector_type(8)));
typedef float  f32x4  __attribute__((ext_vector_type(4)));

namespace {
constexpr int Bn = 4096, Tn = 128, Vn = 30, En = 256, Hn = 128, Gn = 512;
constexpr int WS_LOSS  = 0;
constexpr int WS_MASK  = 1;
constexpr int WS_CNT   = 2;
constexpr int WS_XPROJ = 16;                  // 30*512 fp32, layout [v][k][g]
constexpr int WS_WF_F  = WS_XPROJ + Vn * Gn;  // 65536 bf16 Whh-frags + 4096 bf16 Wlin-frags
constexpr int NBLK = 256;                     // 16 rows per block
}

__device__ __forceinline__ float fexp2(float x) { return __builtin_amdgcn_exp2f(x); }
__device__ __forceinline__ float frcp(float x)  { return __builtin_amdgcn_rcpf(x); }
__device__ __forceinline__ float sigf(float x)  { return frcp(1.f + fexp2(x * -1.44269504f)); }
__device__ __forceinline__ float tanh_(float x) { return 1.f - 2.f * frcp(fexp2(x * 2.88539008f) + 1.f); }

// ---- setup, 94 blocks x 256 (unchanged; zeroes loss/mask/cnt)
__global__ void k_setup(const float* __restrict__ emb, const float* __restrict__ W_ih,
                        const float* __restrict__ b_ih, const float* __restrict__ b_hh,
                        const float* __restrict__ W_hh, const float* __restrict__ W_lin,
                        float* __restrict__ ws) {
  const int bid = blockIdx.x, tid = threadIdx.x;
  if (bid < 60) {
    __shared__ __align__(16) float es[En];
    int v = bid >> 1;
    int j = ((bid & 1) << 8) + tid;   // j = g*128 + k
    es[tid] = emb[v * En + tid];
    __syncthreads();
    float a = b_ih[j] + b_hh[j];
    const float* wr = W_ih + j * En;
#pragma unroll 4
    for (int e = 0; e < En; e += 4) {
      float4 w = *(const float4*)(wr + e);
      float4 x = *(const float4*)(es + e);
      a += x.x * w.x + x.y * w.y + x.z * w.z + x.w * w.w;
    }
    ws[WS_XPROJ + v * Gn + (j & 127) * 4 + (j >> 7)] = a;
  } else if (bid < 92) {
    int fid = (bid - 60) * 256 + tid;  // 0..8191
    int l = fid & 63, kt = (fid >> 6) & 3, g = (fid >> 8) & 3, w = fid >> 10;
    int n  = (g * 8 + w) * 16 + (l & 15);
    int k0 = kt * 32 + (l >> 4) * 8;
    const float* src = W_hh + n * Hn + k0;
    union { __bf16 h[8]; uint4 u; } pk;
#pragma unroll
    for (int j = 0; j < 8; ++j) pk.h[j] = (__bf16)src[j];
    __bf16* wf = (__bf16*)(ws + WS_WF_F);
    *(uint4*)(wf + fid * 8) = pk.u;
  } else {
    int fid = (bid - 92) * 256 + tid;  // 0..511
    if (fid < 3) ws[fid] = 0.f;        // WS_LOSS, WS_MASK, WS_CNT
    int l = fid & 63, kt = (fid >> 6) & 3, n = fid >> 8;
    int col = n * 16 + (l & 15);
    int k0  = kt * 32 + (l >> 4) * 8;
    union { __bf16 h[8]; uint4 u; } pk;
#pragma unroll
    for (int j = 0; j < 8; ++j)
      pk.h[j] = (col < Vn) ? (__bf16)W_lin[col * Hn + k0 + j] : (__bf16)0.f;
    __bf16* wf = (__bf16*)(ws + WS_WF_F);
    *(uint4*)(wf + 65536 + fid * 8) = pk.u;
  }
}

// ---- main: 256 blocks x 1024 threads (16 waves), 16 batch rows/block
__global__ __launch_bounds__(1024)
__attribute__((amdgpu_waves_per_eu(4, 4)))
void k_main(
    const int* __restrict__ inpt, const float* __restrict__ h0,
    const float* __restrict__ c0, const float* __restrict__ maskY,
    const float* __restrict__ b_lin, float* __restrict__ ws,
    float* __restrict__ out) {
  __shared__ __align__(16) __bf16 hbuf[2][16][136];
  __shared__ int   tokL[16 * 129];
  __shared__ float maskL[16 * 132];
  __shared__ __align__(16) float lgP[2][8][256];   // [dbuf][kt*2+nt][lane*4+reg]
  __shared__ __align__(16) float gx[8][64][4];     // GO->IF: {g0,g1,o0,o1} (p=0,1)
  __shared__ __align__(16) float ix[8][64][4];     // IF->GO: {i2,i3,f2,f3} (p=2,3)
  __shared__ float blinL[32];
  __shared__ float red[4];

  const float2* X2  = (const float2*)(ws + WS_XPROJ); // float2 pairs of [v][k][4g]
  const __bf16* wf  = (const __bf16*)(ws + WS_WF_F);
  const __bf16* wlf = wf + 65536;

  const int tid = threadIdx.x;
  const int w = tid >> 6, l = tid & 63, quad = l >> 4, lc = l & 15;
  const int row0 = blockIdx.x * 16;
  const bool isIF = (w < 8);
  const int cw = w & 7;            // col-range index
  const int kh = cw * 16 + lc;     // owned column (within each gate)
  const int prB = isIF ? 0 : 2;    // pointwise p-base: IF rows +0/+1, GO +2/+3
  const int lnt = (w >> 2) & 1, lkt = w & 3;   // logits assignment (IF only)
  const int xoff = isIF ? 0 : 1;   // float2 index offset: (i,f) or (g,o)

  // staging
  for (int idx = tid; idx < 16 * Tn; idx += 1024) {
    int r = idx >> 7, t = idx & 127;
    tokL[r * 129 + t]  = inpt[(row0 + r) * Tn + t];
    maskL[r * 132 + t] = maskY[(row0 + r) * Tn + t];
  }
  for (int idx = tid; idx < 16 * Hn; idx += 1024) {
    int r = idx >> 7, k = idx & 127;
    hbuf[0][r][k] = (__bf16)h0[(row0 + r) * Hn + k];
  }
  if (tid < 32) blinL[tid] = (tid < Vn) ? b_lin[tid] : -1e30f;

  // persistent frags: 2 gate-ntiles (8 frags = 32 regs, AGPR-resident) + 1 W_lin frag
  // ntile n -> setup frag id: g=n>>3, wv=n&7, fid=((wv*4+g)*4+kt)*64+l
  const int n0 = isIF ? cw : 16 + cw;       // i or g
  const int n1 = isIF ? 8 + cw : 24 + cw;   // f or o
  bf16x8 wreg[2][4];
#pragma unroll
  for (int kt = 0; kt < 4; ++kt) {
    wreg[0][kt] = __builtin_bit_cast(bf16x8,
        *(const uint4*)(wf + ((((n0 & 7) * 4 + (n0 >> 3)) * 4 + kt) * 64 + l) * 8));
    wreg[1][kt] = __builtin_bit_cast(bf16x8,
        *(const uint4*)(wf + ((((n1 & 7) * 4 + (n1 >> 3)) * 4 + kt) * 64 + l) * 8));
  }
  bf16x8 wlin = __builtin_bit_cast(bf16x8,
      *(const uint4*)(wlf + ((isIF ? (lnt * 4 + lkt) : 0) * 64 + l) * 8));

  float creg[2];
#pragma unroll
  for (int p = 0; p < 2; ++p)
    creg[p] = c0[(row0 + quad * 4 + prB + p) * Hn + kh];

  float mloc = 0.f;
  if (w == 13) {  // block mask sum: 16 rows x 128 = 512 float4
    float s = 0.f;
    const float4* m4 = (const float4*)(maskY + row0 * Tn);
#pragma unroll
    for (int i = 0; i < 8; ++i) s += m4[l + i * 64].x + m4[l + i * 64].y +
                                     m4[l + i * 64].z + m4[l + i * 64].w;
    mloc = s;
  }
  float ce_acc = 0.f;
  __syncthreads();

  for (int t = 0; t <= Tn; ++t) {  // gates t<=126, logits 1<=t<=127, softmax t>=2
    const int par = t & 1;
    const __bf16* hc = &hbuf[par][0][0];
    __bf16*       hn = &hbuf[par ^ 1][0][0];
    const bool do_g = (t <= Tn - 2);
    const bool do_l = isIF && (t >= 1) && (t <= Tn - 1);

    float2 xv[4];
    if (do_g) {  // Xproj float2 (this wave's 2 gate components), issued first
#pragma unroll
      for (int p = 0; p < 4; ++p)
        xv[p] = X2[(tokL[(quad * 4 + p) * 129 + t] * 128 + kh) * 2 + xoff];
    }
    f32x4 acc[2] = {{0, 0, 0, 0}, {0, 0, 0, 0}};
    if (do_g || do_l) {
      bf16x8 af[4];
#pragma unroll
      for (int kt = 0; kt < 4; ++kt)
        af[kt] = __builtin_bit_cast(bf16x8,
            *(const uint4*)(hc + lc * 136 + kt * 32 + quad * 8));
      if (do_g) {
#pragma unroll
        for (int kt = 0; kt < 4; ++kt) {
          acc[0] = __builtin_amdgcn_mfma_f32_16x16x32_bf16(af[kt], wreg[0][kt], acc[0], 0, 0, 0);
          acc[1] = __builtin_amdgcn_mfma_f32_16x16x32_bf16(af[kt], wreg[1][kt], acc[1], 0, 0, 0);
        }
      }
      if (do_l) {
        f32x4 lacc = {0, 0, 0, 0};
        lacc = __builtin_amdgcn_mfma_f32_16x16x32_bf16(af[lkt], wlin, lacc, 0, 0, 0);
        *(f32x4*)&lgP[par][lkt * 2 + lnt][l * 4] = lacc;
      }
    }
    if (do_g) {
      // add Xproj for this wave's 2 gates, all 4 p
#pragma unroll
      for (int p = 0; p < 4; ++p) {
        acc[0][p] += xv[p].x;
        acc[1][p] += xv[p].y;
      }
      // exchange halves (lane-aligned: same lane id = same (row,col) cell)
      if (isIF)
        *(float4*)&ix[cw][l][0] = float4{acc[0][2], acc[0][3], acc[1][2], acc[1][3]};
      else
        *(float4*)&gx[cw][l][0] = float4{acc[0][0], acc[0][1], acc[1][0], acc[1][1]};
    }
    __syncthreads();  // barrier 1: gate halves exchanged

    if (do_g) {
      float4 pr = isIF ? *(const float4*)&gx[cw][l][0]
                       : *(const float4*)&ix[cw][l][0];
#pragma unroll
      for (int p = 0; p < 2; ++p) {
        float gi = isIF ? acc[0][p] : ((const float*)&pr)[p];
        float gf = isIF ? acc[1][p] : ((const float*)&pr)[2 + p];
        float gg = isIF ? ((const float*)&pr)[p]     : acc[0][p];
        float go = isIF ? ((const float*)&pr)[2 + p] : acc[1][p];
        float c2 = sigf(gf) * creg[p] + sigf(gi) * tanh_(gg);
        float h2 = sigf(go) * tanh_(c2);
        creg[p] = c2;
        hn[(quad * 4 + prB + p) * 136 + kh] = (__bf16)h2;
      }
    }

    // softmax+CE of previous step's logits (waves 14,15; 8 rows each)
    if (w >= 14 && t >= 2) {
      const float* P = &lgP[par ^ 1][0][0];
      int r8 = l >> 3, j = l & 7;
      int row = (w - 14) * 8 + r8;
      float lg[4], mx = -3.4e38f;
#pragma unroll
      for (int i = 0; i < 4; ++i) {
        int v = j * 4 + i;
        int li = ((row >> 2) * 16 + (v & 15)) * 4 + (row & 3);
        float s = blinL[v];
#pragma unroll
        for (int kt = 0; kt < 4; ++kt) s += P[(kt * 2 + (v >> 4)) * 256 + li];
        lg[i] = s;
        mx = fmaxf(mx, s);
      }
      mx = fmaxf(mx, __shfl_xor(mx, 1));
      mx = fmaxf(mx, __shfl_xor(mx, 2));
      mx = fmaxf(mx, __shfl_xor(mx, 4));
      int y = tokL[row * 129 + (t - 1)];
      float e = 0.f, ly = 0.f;
#pragma unroll
      for (int i = 0; i < 4; ++i) {
        e  += fexp2((lg[i] - mx) * 1.44269504f);
        ly += (j * 4 + i == y) ? lg[i] : 0.f;
      }
      e  += __shfl_xor(e, 1);  ly += __shfl_xor(ly, 1);
      e  += __shfl_xor(e, 2);  ly += __shfl_xor(ly, 2);
      e  += __shfl_xor(e, 4);  ly += __shfl_xor(ly, 4);
      if (j == 0)
        ce_acc += ((mx + __logf(e)) - ly) * maskL[row * 132 + (t - 2)];
    }
    __syncthreads();  // barrier 2: h(t+1) published / lgP dbuf safe
  }

  // final reductions
  if (w == 13) {
#pragma unroll
    for (int off = 32; off > 0; off >>= 1) mloc += __shfl_down(mloc, off);
    if (l == 0) red[0] = mloc;
  }
  if (w >= 14) {
#pragma unroll
    for (int off = 32; off > 0; off >>= 1) ce_acc += __shfl_down(ce_acc, off);
    if (l == 0) red[1 + (w - 14)] = ce_acc;
  }
  __syncthreads();
  if (tid == 0) {
    atomicAdd(ws + WS_LOSS, red[1] + red[2]);
    atomicAdd(ws + WS_MASK, red[0]);
    __threadfence();
    unsigned old = atomicAdd((unsigned*)(ws + WS_CNT), 1u);
    if (old == NBLK - 1) {  // last block publishes
      float lv  = atomicAdd(ws + WS_LOSS, 0.f);
      float mv2 = atomicAdd(ws + WS_MASK, 0.f);
      out[0] = lv / mv2;
    }
  }
}

extern "C" void kernel_launch(void* const* d_in, const int* in_sizes, int n_in,
                              void* d_out, int out_size, void* d_ws, size_t ws_size,
                              hipStream_t stream) {
  const int*   inpt  = (const int*)  d_in[0];
  const float* h0    = (const float*)d_in[1];
  const float* c0    = (const float*)d_in[2];
  const float* maskY = (const float*)d_in[3];
  // d_in[4] = beta (unused)
  const float* emb   = (const float*)d_in[5];
  const float* W_ih  = (const float*)d_in[6];
  const float* b_ih  = (const float*)d_in[7];
  const float* W_hh  = (const float*)d_in[8];
  const float* b_hh  = (const float*)d_in[9];
  const float* W_lin = (const float*)d_in[10];
  const float* b_lin = (const float*)d_in[11];
  float* ws  = (float*)d_ws;
  float* out = (float*)d_out;

  hipLaunchKernelGGL(k_setup, dim3(94),   dim3(256),  0, stream,
                     emb, W_ih, b_ih, b_hh, W_hh, W_lin, ws);
  hipLaunchKernelGGL(k_main,  dim3(NBLK), dim3(1024), 0, stream,
                     inpt, h0, c0, maskY, b_lin, ws, out);
}